// Round 1
// baseline (816.047 us; speedup 1.0000x reference)
//
#include <hip/hip_runtime.h>
#include <stdint.h>

#define M_SIMP 100000
#define NNZV   800000
#define KTOT   6

typedef unsigned int u32;

__device__ __forceinline__ float bf2f(u32 u){ return __uint_as_float(u << 16); }
__device__ __forceinline__ u32 f2bf(float f){
    u32 u = __float_as_uint(f);
    return (u + 0x7FFFu + ((u >> 16) & 1u)) >> 16;   // RNE
}

// ---------------- CSR build ----------------
__global__ void k_hist(const int* __restrict__ rows, int* __restrict__ cnt, int n){
    int e = blockIdx.x * 256 + threadIdx.x;
    if (e < n) atomicAdd(&cnt[rows[e]], 1);
}

// exclusive scan, 1024 elems/block
__global__ void k_scan1(const int* __restrict__ in, int* __restrict__ out,
                        int* __restrict__ bsums, int n){
    __shared__ int s[256];
    int t = threadIdx.x;
    int base = blockIdx.x * 1024 + t * 4;
    int v0 = (base + 0 < n) ? in[base + 0] : 0;
    int v1 = (base + 1 < n) ? in[base + 1] : 0;
    int v2 = (base + 2 < n) ? in[base + 2] : 0;
    int v3 = (base + 3 < n) ? in[base + 3] : 0;
    int sum = v0 + v1 + v2 + v3;
    s[t] = sum;
    __syncthreads();
    for (int off = 1; off < 256; off <<= 1){
        int x = (t >= off) ? s[t - off] : 0;
        __syncthreads();
        s[t] += x;
        __syncthreads();
    }
    int excl = s[t] - sum;
    if (t == 255) bsums[blockIdx.x] = s[255];
    if (base + 0 < n) out[base + 0] = excl;
    if (base + 1 < n) out[base + 1] = excl + v0;
    if (base + 2 < n) out[base + 2] = excl + v0 + v1;
    if (base + 3 < n) out[base + 3] = excl + v0 + v1 + v2;
}

__global__ void k_scan2(int* __restrict__ bsums, int nb){
    if (threadIdx.x == 0){
        int run = 0;
        for (int i = 0; i < nb; i++){ int x = bsums[i]; bsums[i] = run; run += x; }
    }
}

__global__ void k_scan3(int* __restrict__ out, const int* __restrict__ bsums, int n){
    int base = blockIdx.x * 1024 + threadIdx.x * 4;
    int add = bsums[blockIdx.x];
    #pragma unroll
    for (int j = 0; j < 4; j++)
        if (base + j < n) out[base + j] += add;
}

// copy row_ptr -> cursor, set row_ptr[M]=NNZ
__global__ void k_prepfill(int* __restrict__ rp, int* __restrict__ cur){
    int i = blockIdx.x * 256 + threadIdx.x;
    if (i < M_SIMP) cur[i] = rp[i];
    if (i == 0) rp[M_SIMP] = NNZV;
}

__global__ void k_fill(const int* __restrict__ rows, const int* __restrict__ cols,
                       const float* __restrict__ vals, int* __restrict__ cursor,
                       int* __restrict__ ccol, float* __restrict__ cval, int n){
    int e = blockIdx.x * 256 + threadIdx.x;
    if (e < n){
        int r = rows[e];
        int p = atomicAdd(&cursor[r], 1);
        ccol[p] = cols[e];
        cval[p] = vals[e];
    }
}

// ---------------- transpose x (B,C,M) fp32 -> F0 (M,128) bf16 ----------------
__global__ void k_transpose(const float* __restrict__ x, u32* __restrict__ F0){
    __shared__ unsigned short s[64 * 130];
    int t = threadIdx.x;
    int m0 = blockIdx.x * 64;
    int j  = t & 63;      // m within tile (load), uint col (store)
    int r4 = t >> 6;      // 0..3
    #pragma unroll 4
    for (int it = 0; it < 32; ++it){
        int bc = it * 4 + r4;
        int m  = m0 + j;
        if (m < M_SIMP)
            s[j * 130 + bc] = (unsigned short)f2bf(x[(size_t)bc * M_SIMP + m]);
    }
    __syncthreads();
    #pragma unroll 4
    for (int it = 0; it < 16; ++it){
        int m  = it * 4 + r4;
        int gm = m0 + m;
        if (gm < M_SIMP){
            u32 lo = s[m * 130 + 2 * j];
            u32 hi = s[m * 130 + 2 * j + 1];
            F0[(size_t)gm * 64 + j] = lo | (hi << 16);
        }
    }
}

// ---------------- SpMM: fout[m] = sum val * fin[col], 128 bf16 ch ----------------
__global__ void k_spmm(const int* __restrict__ rp, const int* __restrict__ ccol,
                       const float* __restrict__ cval,
                       const u32* __restrict__ fin, u32* __restrict__ fout){
    int row  = blockIdx.x * 4 + (threadIdx.x >> 6);
    int lane = threadIdx.x & 63;
    if (row >= M_SIMP) return;
    int s = rp[row], e = rp[row + 1];
    float a0 = 0.f, a1 = 0.f;
    for (int j = s; j < e; j++){
        int   c = ccol[j];
        float v = cval[j];
        u32 g = fin[(size_t)c * 64 + lane];
        a0 += v * bf2f(g & 0xffffu);
        a1 += v * bf2f(g >> 16);
    }
    fout[(size_t)row * 64 + lane] = f2bf(a0) | (f2bf(a1) << 16);
}

// ---------------- theta (o,i,k) -> Wt [k][i][o] ----------------
__global__ void k_wt(const float* __restrict__ theta, float* __restrict__ Wt){
    int idx = blockIdx.x * 256 + threadIdx.x;
    if (idx < 64 * 64 * KTOT){
        int k = idx >> 12;          // /4096
        int r = idx & 4095;
        int i = r >> 6;
        int o = r & 63;
        Wt[idx] = theta[o * 384 + i * 6 + k];
    }
}

// ---------------- final GEMM: out[b,o,m] = sum_k sum_i Wt[k][i][o]*F_k[m][b*64+i] ----------------
__global__ __launch_bounds__(256) void k_gemm(
    const u32* __restrict__ F0, const u32* __restrict__ F1, const u32* __restrict__ F2,
    const u32* __restrict__ F4, const u32* __restrict__ F5,
    const float* __restrict__ Wt, const float* __restrict__ bias,
    float* __restrict__ out)
{
    __shared__ __align__(16) float sW[64 * 64];
    __shared__ __align__(16) float sF[64 * 68];
    int t  = threadIdx.x;
    int bm = blockIdx.x * 64;
    int b  = blockIdx.y;
    const u32* Fs[6] = {F0, F1, F2, F0, F4, F5};
    float acc[4][4];
    #pragma unroll
    for (int a = 0; a < 4; a++)
        #pragma unroll
        for (int c = 0; c < 4; c++) acc[a][c] = 0.f;
    int og = t & 15, mg = t >> 4;
    int o0 = og * 4, m0 = mg * 4;

    #pragma unroll
    for (int k = 0; k < KTOT; k++){
        // stage W_k: [i][o] 16 KB, coalesced
        const float4* Wk = (const float4*)(Wt + k * 4096);
        float4* sW4 = (float4*)sW;
        sW4[t]       = Wk[t];
        sW4[256 + t] = Wk[256 + t];
        sW4[512 + t] = Wk[512 + t];
        sW4[768 + t] = Wk[768 + t];
        // stage F_k tile: LDS [i][m], stride 68
        const u32* Fk = Fs[k];
        #pragma unroll
        for (int jj = 0; jj < 2; jj++){
            int u  = jj * 256 + t;
            int m  = u >> 3;
            int i8 = (u & 7) << 3;
            int gm = bm + m;
            uint4 g = make_uint4(0u, 0u, 0u, 0u);
            if (gm < M_SIMP)
                g = *(const uint4*)(Fk + (size_t)gm * 64 + b * 32 + (i8 >> 1));
            int base = i8 * 68 + m;
            sF[base + 0 * 68] = bf2f(g.x & 0xffffu);
            sF[base + 1 * 68] = bf2f(g.x >> 16);
            sF[base + 2 * 68] = bf2f(g.y & 0xffffu);
            sF[base + 3 * 68] = bf2f(g.y >> 16);
            sF[base + 4 * 68] = bf2f(g.z & 0xffffu);
            sF[base + 5 * 68] = bf2f(g.z >> 16);
            sF[base + 6 * 68] = bf2f(g.w & 0xffffu);
            sF[base + 7 * 68] = bf2f(g.w >> 16);
        }
        __syncthreads();
        #pragma unroll 8
        for (int i = 0; i < 64; i++){
            const float4 w = *(const float4*)&sW[i * 64 + o0];
            const float4 f = *(const float4*)&sF[i * 68 + m0];
            acc[0][0] += f.x * w.x; acc[0][1] += f.x * w.y; acc[0][2] += f.x * w.z; acc[0][3] += f.x * w.w;
            acc[1][0] += f.y * w.x; acc[1][1] += f.y * w.y; acc[1][2] += f.y * w.z; acc[1][3] += f.y * w.w;
            acc[2][0] += f.z * w.x; acc[2][1] += f.z * w.y; acc[2][2] += f.z * w.z; acc[2][3] += f.z * w.w;
            acc[3][0] += f.w * w.x; acc[3][1] += f.w * w.y; acc[3][2] += f.w * w.z; acc[3][3] += f.w * w.w;
        }
        __syncthreads();
    }

    float bv0 = bias[o0], bv1 = bias[o0 + 1], bv2 = bias[o0 + 2], bv3 = bias[o0 + 3];
    float bvs[4] = {bv0, bv1, bv2, bv3};
    #pragma unroll
    for (int oi = 0; oi < 4; oi++){
        size_t rowbase = (size_t)(b * 64 + o0 + oi) * M_SIMP;
        #pragma unroll
        for (int mi = 0; mi < 4; mi++){
            int gm = bm + m0 + mi;
            if (gm < M_SIMP) out[rowbase + gm] = acc[mi][oi] + bvs[oi];
        }
    }
}

extern "C" void kernel_launch(void* const* d_in, const int* in_sizes, int n_in,
                              void* d_out, int out_size, void* d_ws, size_t ws_size,
                              hipStream_t stream)
{
    const int*   Ll_idx = (const int*)d_in[0];
    const float* Ll_val = (const float*)d_in[1];
    const int*   Lu_idx = (const int*)d_in[2];
    const float* Lu_val = (const float*)d_in[3];
    const float* x      = (const float*)d_in[4];
    const float* theta  = (const float*)d_in[5];
    const float* bias   = (const float*)d_in[6];
    float* out = (float*)d_out;

    char* ws = (char*)d_ws;
    size_t off = 0;
    auto take = [&](size_t bytes) -> char* {
        char* p = ws + off;
        off = (off + bytes + 255) & ~(size_t)255;
        return p;
    };
    const size_t FB = (size_t)M_SIMP * 128 * 2;   // 25.6 MB per feature map (bf16)
    u32* F0 = (u32*)take(FB);
    u32* F1 = (u32*)take(FB);
    u32* F2 = (u32*)take(FB);
    u32* F4 = (u32*)take(FB);
    u32* F5 = (u32*)take(FB);
    float* Wt = (float*)take(64 * 64 * KTOT * 4);
    int* cnt_l = (int*)take((size_t)M_SIMP * 4);       // doubles as cursor
    int* cnt_u = (int*)take((size_t)M_SIMP * 4);
    int* rp_l  = (int*)take((size_t)(M_SIMP + 1) * 4);
    int* rp_u  = (int*)take((size_t)(M_SIMP + 1) * 4);
    int* ccol_l = (int*)take((size_t)NNZV * 4);
    float* cval_l = (float*)take((size_t)NNZV * 4);
    int* ccol_u = (int*)take((size_t)NNZV * 4);
    float* cval_u = (float*)take((size_t)NNZV * 4);
    int* bs_l = (int*)take(512);
    int* bs_u = (int*)take(512);

    hipMemsetAsync(cnt_l, 0, (size_t)M_SIMP * 4, stream);
    hipMemsetAsync(cnt_u, 0, (size_t)M_SIMP * 4, stream);

    const int NBH = (NNZV + 255) / 256;       // 3125
    k_hist<<<NBH, 256, 0, stream>>>(Ll_idx, cnt_l, NNZV);
    k_hist<<<NBH, 256, 0, stream>>>(Lu_idx, cnt_u, NNZV);

    const int NBS = (M_SIMP + 1023) / 1024;   // 98
    k_scan1<<<NBS, 256, 0, stream>>>(cnt_l, rp_l, bs_l, M_SIMP);
    k_scan1<<<NBS, 256, 0, stream>>>(cnt_u, rp_u, bs_u, M_SIMP);
    k_scan2<<<1, 64, 0, stream>>>(bs_l, NBS);
    k_scan2<<<1, 64, 0, stream>>>(bs_u, NBS);
    k_scan3<<<NBS, 256, 0, stream>>>(rp_l, bs_l, M_SIMP);
    k_scan3<<<NBS, 256, 0, stream>>>(rp_u, bs_u, M_SIMP);

    const int NBP = (M_SIMP + 255) / 256;     // 391
    k_prepfill<<<NBP, 256, 0, stream>>>(rp_l, cnt_l);
    k_prepfill<<<NBP, 256, 0, stream>>>(rp_u, cnt_u);
    k_fill<<<NBH, 256, 0, stream>>>(Ll_idx, Ll_idx + NNZV, Ll_val, cnt_l, ccol_l, cval_l, NNZV);
    k_fill<<<NBH, 256, 0, stream>>>(Lu_idx, Lu_idx + NNZV, Lu_val, cnt_u, ccol_u, cval_u, NNZV);

    const int NBT = (M_SIMP + 63) / 64;       // 1563
    k_transpose<<<NBT, 256, 0, stream>>>(x, F0);

    const int NBM = (M_SIMP + 3) / 4;         // 25000
    k_spmm<<<NBM, 256, 0, stream>>>(rp_l, ccol_l, cval_l, F0, F1);
    k_spmm<<<NBM, 256, 0, stream>>>(rp_l, ccol_l, cval_l, F1, F2);
    k_spmm<<<NBM, 256, 0, stream>>>(rp_u, ccol_u, cval_u, F0, F4);
    k_spmm<<<NBM, 256, 0, stream>>>(rp_u, ccol_u, cval_u, F4, F5);

    k_wt<<<(64 * 64 * KTOT + 255) / 256, 256, 0, stream>>>(theta, Wt);

    dim3 gg(NBT, 2);
    k_gemm<<<gg, 256, 0, stream>>>(F0, F1, F2, F4, F5, Wt, bias, out);
}

// Round 2
// 560.438 us; speedup vs baseline: 1.4561x; 1.4561x over previous
//
#include <hip/hip_runtime.h>
#include <stdint.h>

#define M_SIMP 100000
#define MPAD   100064     // 64-row pad so last GEMM tile reads in-bounds garbage
#define NNZV   800000
#define KTOT   6

typedef unsigned int u32;
typedef __attribute__((ext_vector_type(8))) short short8;
typedef __attribute__((ext_vector_type(4))) float f32x4;

__device__ __forceinline__ float bf2f(u32 u){ return __uint_as_float(u << 16); }
__device__ __forceinline__ u32 f2bf(float f){
    u32 u = __float_as_uint(f);
    return (u + 0x7FFFu + ((u >> 16) & 1u)) >> 16;   // RNE
}

// ---------------- CSR build (both Laplacians via blockIdx.y) ----------------
__global__ void k_hist(const int* __restrict__ r0, const int* __restrict__ r1,
                       int* __restrict__ c0, int* __restrict__ c1){
    int e = blockIdx.x * 256 + threadIdx.x;
    const int* r = blockIdx.y ? r1 : r0;
    int* c = blockIdx.y ? c1 : c0;
    if (e < NNZV) atomicAdd(&c[r[e]], 1);
}

// exclusive scan, 1024 elems/block
__global__ void k_scan1(const int* __restrict__ in0, int* __restrict__ out0, int* __restrict__ bs0,
                        const int* __restrict__ in1, int* __restrict__ out1, int* __restrict__ bs1,
                        int n){
    const int* in  = blockIdx.y ? in1 : in0;
    int* out   = blockIdx.y ? out1 : out0;
    int* bsums = blockIdx.y ? bs1 : bs0;
    __shared__ int s[256];
    int t = threadIdx.x;
    int base = blockIdx.x * 1024 + t * 4;
    int v0 = (base + 0 < n) ? in[base + 0] : 0;
    int v1 = (base + 1 < n) ? in[base + 1] : 0;
    int v2 = (base + 2 < n) ? in[base + 2] : 0;
    int v3 = (base + 3 < n) ? in[base + 3] : 0;
    int sum = v0 + v1 + v2 + v3;
    s[t] = sum;
    __syncthreads();
    for (int off = 1; off < 256; off <<= 1){
        int x = (t >= off) ? s[t - off] : 0;
        __syncthreads();
        s[t] += x;
        __syncthreads();
    }
    int excl = s[t] - sum;
    if (t == 255) bsums[blockIdx.x] = s[255];
    if (base + 0 < n) out[base + 0] = excl;
    if (base + 1 < n) out[base + 1] = excl + v0;
    if (base + 2 < n) out[base + 2] = excl + v0 + v1;
    if (base + 3 < n) out[base + 3] = excl + v0 + v1 + v2;
}

__global__ void k_scan2(int* __restrict__ b0, int* __restrict__ b1, int nb){
    int t = threadIdx.x;
    if (t < 2){
        int* bs = t ? b1 : b0;
        int run = 0;
        for (int i = 0; i < nb; i++){ int x = bs[i]; bs[i] = run; run += x; }
    }
}

__global__ void k_scan3(int* __restrict__ o0, const int* __restrict__ b0,
                        int* __restrict__ o1, const int* __restrict__ b1, int n){
    int* out = blockIdx.y ? o1 : o0;
    const int* bsums = blockIdx.y ? b1 : b0;
    int base = blockIdx.x * 1024 + threadIdx.x * 4;
    int add = bsums[blockIdx.x];
    #pragma unroll
    for (int j = 0; j < 4; j++)
        if (base + j < n) out[base + j] += add;
}

__global__ void k_prepfill(int* __restrict__ rp0, int* __restrict__ cur0,
                           int* __restrict__ rp1, int* __restrict__ cur1){
    int* rp  = blockIdx.y ? rp1 : rp0;
    int* cur = blockIdx.y ? cur1 : cur0;
    int i = blockIdx.x * 256 + threadIdx.x;
    if (i < M_SIMP) cur[i] = rp[i];
    if (i == 0) rp[M_SIMP] = NNZV;
}

// fill (col,val) interleaved as uint2
__global__ void k_fill(const int* __restrict__ idx0, const float* __restrict__ val0,
                       int* __restrict__ cur0, uint2* __restrict__ cp0,
                       const int* __restrict__ idx1, const float* __restrict__ val1,
                       int* __restrict__ cur1, uint2* __restrict__ cp1){
    const int* idx = blockIdx.y ? idx1 : idx0;
    const float* val = blockIdx.y ? val1 : val0;
    int* cursor = blockIdx.y ? cur1 : cur0;
    uint2* cp = blockIdx.y ? cp1 : cp0;
    int e = blockIdx.x * 256 + threadIdx.x;
    if (e < NNZV){
        int r = idx[e];                 // row
        int c = idx[NNZV + e];          // col
        int p = atomicAdd(&cursor[r], 1);
        cp[p] = make_uint2((u32)c, __float_as_uint(val[e]));
    }
}

// ---------------- transpose x (B,C,M) fp32 -> F0 (M,128) bf16 ----------------
__global__ void k_transpose(const float* __restrict__ x, u32* __restrict__ F0){
    __shared__ unsigned short s[64 * 130];
    int t = threadIdx.x;
    int m0 = blockIdx.x * 64;
    int j  = t & 63;
    int r4 = t >> 6;
    #pragma unroll 4
    for (int it = 0; it < 32; ++it){
        int bc = it * 4 + r4;
        int m  = m0 + j;
        if (m < M_SIMP)
            s[j * 130 + bc] = (unsigned short)f2bf(x[(size_t)bc * M_SIMP + m]);
    }
    __syncthreads();
    #pragma unroll 4
    for (int it = 0; it < 16; ++it){
        int m  = it * 4 + r4;
        int gm = m0 + m;
        if (gm < M_SIMP){
            u32 lo = s[m * 130 + 2 * j];
            u32 hi = s[m * 130 + 2 * j + 1];
            F0[(size_t)gm * 64 + j] = lo | (hi << 16);
        }
    }
}

// ---------------- SpMM: both chains in one launch, unroll-4 ILP ----------------
__global__ __launch_bounds__(256) void k_spmm(
    const int* __restrict__ rpA, const uint2* __restrict__ cpA,
    const u32* __restrict__ finA, u32* __restrict__ foutA,
    const int* __restrict__ rpB, const uint2* __restrict__ cpB,
    const u32* __restrict__ finB, u32* __restrict__ foutB)
{
    int lane = threadIdx.x & 63;
    int row  = blockIdx.x * 4 + (threadIdx.x >> 6);
    if (row >= M_SIMP) return;
    const int* rp; const uint2* cp; const u32* fin; u32* fout;
    if (blockIdx.y == 0){ rp = rpA; cp = cpA; fin = finA; fout = foutA; }
    else                { rp = rpB; cp = cpB; fin = finB; fout = foutB; }
    int s = rp[row], e = rp[row + 1];
    float a0 = 0.f, a1 = 0.f;
    int j = s;
    for (; j + 4 <= e; j += 4){
        uint2 p0 = cp[j], p1 = cp[j+1], p2 = cp[j+2], p3 = cp[j+3];
        u32 g0 = fin[(size_t)p0.x * 64 + lane];
        u32 g1 = fin[(size_t)p1.x * 64 + lane];
        u32 g2 = fin[(size_t)p2.x * 64 + lane];
        u32 g3 = fin[(size_t)p3.x * 64 + lane];
        float v0 = __uint_as_float(p0.y), v1 = __uint_as_float(p1.y);
        float v2 = __uint_as_float(p2.y), v3 = __uint_as_float(p3.y);
        a0 += v0 * bf2f(g0 & 0xffffu) + v1 * bf2f(g1 & 0xffffu)
            + v2 * bf2f(g2 & 0xffffu) + v3 * bf2f(g3 & 0xffffu);
        a1 += v0 * bf2f(g0 >> 16) + v1 * bf2f(g1 >> 16)
            + v2 * bf2f(g2 >> 16) + v3 * bf2f(g3 >> 16);
    }
    for (; j < e; j++){
        uint2 p = cp[j];
        u32 g = fin[(size_t)p.x * 64 + lane];
        float v = __uint_as_float(p.y);
        a0 += v * bf2f(g & 0xffffu);
        a1 += v * bf2f(g >> 16);
    }
    fout[(size_t)row * 64 + lane] = f2bf(a0) | (f2bf(a1) << 16);
}

// ---------------- theta (o,i,k) fp32 -> Wb bf16 [k][o][i] packed u32 ----------------
__global__ void k_wb(const float* __restrict__ theta, u32* __restrict__ Wb){
    int idx = blockIdx.x * 256 + threadIdx.x;    // over 6*64*32 u32
    if (idx < KTOT * 64 * 32){
        int km = idx >> 11;            // /(64*32)
        int r  = idx & 2047;
        int o  = r >> 5;
        int i2 = (r & 31) * 2;
        u32 lo = f2bf(theta[o * 384 + i2 * 6 + km]);
        u32 hi = f2bf(theta[o * 384 + (i2 + 1) * 6 + km]);
        Wb[idx] = lo | (hi << 16);
    }
}

// ---------------- MFMA GEMM: D[o][m] = sum_k W[o][k] * F[k][m] ----------------
// A-frag (o side): Wb[k][o][i], lane&15 = o, 8 consecutive i  -> 16B load
// B-frag (m side): F[m][i],     lane&15 = m, 8 consecutive i  -> 16B load
// C/D: col(lane&15) = m (coalesced store), row(q*4+r) = o
__global__ __launch_bounds__(256) void k_gemm(
    const u32* __restrict__ F0, const u32* __restrict__ F1, const u32* __restrict__ F2,
    const u32* __restrict__ F4, const u32* __restrict__ F5,
    const u32* __restrict__ Wb, const float* __restrict__ bias, float* __restrict__ out)
{
    int t    = threadIdx.x;
    int wave = t >> 6;           // o-subtile 0..3
    int lane = t & 63;
    int q    = lane >> 4;        // 0..3
    int l16  = lane & 15;
    int bm   = blockIdx.x * 64;
    int b    = blockIdx.y;
    const u32* __restrict__ Fs[6] = {F0, F1, F2, F0, F4, F5};

    f32x4 acc0 = {0.f,0.f,0.f,0.f}, acc1 = {0.f,0.f,0.f,0.f};
    f32x4 acc2 = {0.f,0.f,0.f,0.f}, acc3 = {0.f,0.f,0.f,0.f};

    int o_a = wave * 16 + l16;
    size_t mr0 = (size_t)(bm +  0 + l16) * 64 + b * 32;
    size_t mr1 = (size_t)(bm + 16 + l16) * 64 + b * 32;
    size_t mr2 = (size_t)(bm + 32 + l16) * 64 + b * 32;
    size_t mr3 = (size_t)(bm + 48 + l16) * 64 + b * 32;

    #pragma unroll
    for (int km = 0; km < KTOT; km++){
        const u32* __restrict__ F = Fs[km];
        const u32* __restrict__ W = Wb + (km * 64 + o_a) * 32;
        #pragma unroll
        for (int h = 0; h < 2; h++){
            int koff = h * 16 + q * 4;
            short8 a  = *(const short8*)(W + koff);
            short8 bb0 = *(const short8*)(F + mr0 + koff);
            short8 bb1 = *(const short8*)(F + mr1 + koff);
            short8 bb2 = *(const short8*)(F + mr2 + koff);
            short8 bb3 = *(const short8*)(F + mr3 + koff);
            acc0 = __builtin_amdgcn_mfma_f32_16x16x32_bf16(a, bb0, acc0, 0, 0, 0);
            acc1 = __builtin_amdgcn_mfma_f32_16x16x32_bf16(a, bb1, acc1, 0, 0, 0);
            acc2 = __builtin_amdgcn_mfma_f32_16x16x32_bf16(a, bb2, acc2, 0, 0, 0);
            acc3 = __builtin_amdgcn_mfma_f32_16x16x32_bf16(a, bb3, acc3, 0, 0, 0);
        }
    }

    int ob = wave * 16 + q * 4;
    float bv0 = bias[ob], bv1 = bias[ob+1], bv2 = bias[ob+2], bv3 = bias[ob+3];
    f32x4 accs[4] = {acc0, acc1, acc2, acc3};
    #pragma unroll
    for (int ms = 0; ms < 4; ms++){
        int gm = bm + ms * 16 + l16;
        if (gm < M_SIMP){
            size_t base = (size_t)(b * 64 + ob) * M_SIMP + gm;
            out[base               ] = accs[ms][0] + bv0;
            out[base + 1ul*M_SIMP  ] = accs[ms][1] + bv1;
            out[base + 2ul*M_SIMP  ] = accs[ms][2] + bv2;
            out[base + 3ul*M_SIMP  ] = accs[ms][3] + bv3;
        }
    }
}

extern "C" void kernel_launch(void* const* d_in, const int* in_sizes, int n_in,
                              void* d_out, int out_size, void* d_ws, size_t ws_size,
                              hipStream_t stream)
{
    const int*   Ll_idx = (const int*)d_in[0];
    const float* Ll_val = (const float*)d_in[1];
    const int*   Lu_idx = (const int*)d_in[2];
    const float* Lu_val = (const float*)d_in[3];
    const float* x      = (const float*)d_in[4];
    const float* theta  = (const float*)d_in[5];
    const float* bias   = (const float*)d_in[6];
    float* out = (float*)d_out;

    char* ws = (char*)d_ws;
    size_t off = 0;
    auto take = [&](size_t bytes) -> char* {
        char* p = ws + off;
        off = (off + bytes + 255) & ~(size_t)255;
        return p;
    };
    const size_t FB = (size_t)MPAD * 64 * 4;   // padded bf16 feature map
    u32* F0 = (u32*)take(FB);
    u32* F1 = (u32*)take(FB);
    u32* F2 = (u32*)take(FB);
    u32* F4 = (u32*)take(FB);
    u32* F5 = (u32*)take(FB);
    u32* Wb = (u32*)take((size_t)KTOT * 64 * 32 * 4);
    int* cnt_l = (int*)take((size_t)M_SIMP * 4);   // doubles as cursor
    int* cnt_u = (int*)take((size_t)M_SIMP * 4);
    int* rp_l  = (int*)take((size_t)(M_SIMP + 1) * 4);
    int* rp_u  = (int*)take((size_t)(M_SIMP + 1) * 4);
    uint2* cp_l = (uint2*)take((size_t)NNZV * 8);
    uint2* cp_u = (uint2*)take((size_t)NNZV * 8);
    int* bs_l = (int*)take(512);
    int* bs_u = (int*)take(512);

    hipMemsetAsync(cnt_l, 0, (size_t)M_SIMP * 4, stream);
    hipMemsetAsync(cnt_u, 0, (size_t)M_SIMP * 4, stream);

    const int NBH = (NNZV + 255) / 256;       // 3125
    dim3 gh(NBH, 2);
    k_hist<<<gh, 256, 0, stream>>>(Ll_idx, Lu_idx, cnt_l, cnt_u);

    const int NBS = (M_SIMP + 1023) / 1024;   // 98
    dim3 gs(NBS, 2);
    k_scan1<<<gs, 256, 0, stream>>>(cnt_l, rp_l, bs_l, cnt_u, rp_u, bs_u, M_SIMP);
    k_scan2<<<1, 64, 0, stream>>>(bs_l, bs_u, NBS);
    k_scan3<<<gs, 256, 0, stream>>>(rp_l, bs_l, rp_u, bs_u, M_SIMP);

    const int NBP = (M_SIMP + 255) / 256;     // 391
    dim3 gp(NBP, 2);
    k_prepfill<<<gp, 256, 0, stream>>>(rp_l, cnt_l, rp_u, cnt_u);
    k_fill<<<gh, 256, 0, stream>>>(Ll_idx, Ll_val, cnt_l, cp_l,
                                   Lu_idx, Lu_val, cnt_u, cp_u);

    const int NBT = (M_SIMP + 63) / 64;       // 1563
    k_transpose<<<NBT, 256, 0, stream>>>(x, F0);
    k_wb<<<(KTOT * 64 * 32 + 255) / 256, 256, 0, stream>>>(theta, Wb);

    const int NBM = (M_SIMP + 3) / 4;         // 25000
    dim3 gm(NBM, 2);
    // step 1: F1 = Ll*F0  ||  F4 = Lu*F0
    k_spmm<<<gm, 256, 0, stream>>>(rp_l, cp_l, F0, F1, rp_u, cp_u, F0, F4);
    // step 2: F2 = Ll*F1  ||  F5 = Lu*F4
    k_spmm<<<gm, 256, 0, stream>>>(rp_l, cp_l, F1, F2, rp_u, cp_u, F4, F5);

    dim3 gg(NBT, 2);
    k_gemm<<<gg, 256, 0, stream>>>(F0, F1, F2, F4, F5, Wb, bias, out);
}

// Round 3
// 510.600 us; speedup vs baseline: 1.5982x; 1.0976x over previous
//
#include <hip/hip_runtime.h>
#include <stdint.h>

#define M_SIMP 100000
#define MPAD   100064
#define NNZV   800000
#define KTOT   6

typedef unsigned int u32;
typedef __attribute__((ext_vector_type(8))) short short8;
typedef __attribute__((ext_vector_type(4))) float f32x4;

__device__ __forceinline__ float bf2f(u32 u){ return __uint_as_float(u << 16); }
__device__ __forceinline__ u32 f2bf(float f){
    u32 u = __float_as_uint(f);
    return (u + 0x7FFFu + ((u >> 16) & 1u)) >> 16;   // RNE
}

// ---------------- pass 1: histogram + within-row rank (one atomic pass) ----
__global__ void k_histpe(const int* __restrict__ i0, int* __restrict__ c0, int* __restrict__ p0,
                         const int* __restrict__ i1, int* __restrict__ c1, int* __restrict__ p1){
    int e = blockIdx.x * 256 + threadIdx.x;
    const int* idx = blockIdx.y ? i1 : i0;
    int* cnt = blockIdx.y ? c1 : c0;
    int* pe  = blockIdx.y ? p1 : p0;
    if (e < NNZV){
        int r = idx[e];
        pe[e] = atomicAdd(&cnt[r], 1);
    }
}

// exclusive scan, 1024 elems/block
__global__ void k_scan1(const int* __restrict__ in0, int* __restrict__ out0, int* __restrict__ bs0,
                        const int* __restrict__ in1, int* __restrict__ out1, int* __restrict__ bs1,
                        int n){
    const int* in  = blockIdx.y ? in1 : in0;
    int* out   = blockIdx.y ? out1 : out0;
    int* bsums = blockIdx.y ? bs1 : bs0;
    __shared__ int s[256];
    int t = threadIdx.x;
    int base = blockIdx.x * 1024 + t * 4;
    int v0 = (base + 0 < n) ? in[base + 0] : 0;
    int v1 = (base + 1 < n) ? in[base + 1] : 0;
    int v2 = (base + 2 < n) ? in[base + 2] : 0;
    int v3 = (base + 3 < n) ? in[base + 3] : 0;
    int sum = v0 + v1 + v2 + v3;
    s[t] = sum;
    __syncthreads();
    for (int off = 1; off < 256; off <<= 1){
        int x = (t >= off) ? s[t - off] : 0;
        __syncthreads();
        s[t] += x;
        __syncthreads();
    }
    int excl = s[t] - sum;
    if (t == 255) bsums[blockIdx.x] = s[255];
    if (base + 0 < n) out[base + 0] = excl;
    if (base + 1 < n) out[base + 1] = excl + v0;
    if (base + 2 < n) out[base + 2] = excl + v0 + v1;
    if (base + 3 < n) out[base + 3] = excl + v0 + v1 + v2;
}

__global__ void k_scan2(int* __restrict__ b0, int* __restrict__ b1,
                        int* __restrict__ rp0, int* __restrict__ rp1, int nb){
    int t = threadIdx.x;
    if (t < 2){
        int* bs = t ? b1 : b0;
        int run = 0;
        for (int i = 0; i < nb; i++){ int x = bs[i]; bs[i] = run; run += x; }
    }
    if (t == 2) rp0[M_SIMP] = NNZV;
    if (t == 3) rp1[M_SIMP] = NNZV;
}

__global__ void k_scan3(int* __restrict__ o0, const int* __restrict__ b0,
                        int* __restrict__ o1, const int* __restrict__ b1, int n){
    int* out = blockIdx.y ? o1 : o0;
    const int* bsums = blockIdx.y ? b1 : b0;
    int base = blockIdx.x * 1024 + threadIdx.x * 4;
    int add = bsums[blockIdx.x];
    #pragma unroll
    for (int j = 0; j < 4; j++)
        if (base + j < n) out[base + j] += add;
}

// ---------------- pass 2: 4B perm scatter ----------------
__global__ void k_perm(const int* __restrict__ i0, const int* __restrict__ pe0,
                       const int* __restrict__ rp0, int* __restrict__ pm0,
                       const int* __restrict__ i1, const int* __restrict__ pe1,
                       const int* __restrict__ rp1, int* __restrict__ pm1){
    int e = blockIdx.x * 256 + threadIdx.x;
    const int* idx = blockIdx.y ? i1 : i0;
    const int* pe  = blockIdx.y ? pe1 : pe0;
    const int* rp  = blockIdx.y ? rp1 : rp0;
    int* perm = blockIdx.y ? pm1 : pm0;
    if (e < NNZV){
        int r = idx[e];
        perm[rp[r] + pe[e]] = e;
    }
}

// ---------------- transpose x (B,C,M) fp32 -> F0 (M,128) bf16 ----------------
__global__ void k_transpose(const float* __restrict__ x, u32* __restrict__ F0){
    __shared__ unsigned short s[64 * 130];
    int t = threadIdx.x;
    int m0 = blockIdx.x * 64;
    int j  = t & 63;
    int r4 = t >> 6;
    #pragma unroll 4
    for (int it = 0; it < 32; ++it){
        int bc = it * 4 + r4;
        int m  = m0 + j;
        if (m < M_SIMP)
            s[j * 130 + bc] = (unsigned short)f2bf(x[(size_t)bc * M_SIMP + m]);
    }
    __syncthreads();
    #pragma unroll 4
    for (int it = 0; it < 16; ++it){
        int m  = it * 4 + r4;
        int gm = m0 + m;
        if (gm < M_SIMP){
            u32 lo = s[m * 130 + 2 * j];
            u32 hi = s[m * 130 + 2 * j + 1];
            F0[(size_t)gm * 64 + j] = lo | (hi << 16);
        }
    }
}

// ---------------- SpMM via perm indirection, uint4 gathers ----------------
// 16 rows/block; each row served by 16 lanes x uint4 (8 channels each)
__global__ __launch_bounds__(256) void k_spmm(
    const int* __restrict__ rpA, const int* __restrict__ pmA,
    const int* __restrict__ colA, const float* __restrict__ valA,
    const u32* __restrict__ finA, u32* __restrict__ foutA,
    const int* __restrict__ rpB, const int* __restrict__ pmB,
    const int* __restrict__ colB, const float* __restrict__ valB,
    const u32* __restrict__ finB, u32* __restrict__ foutB)
{
    int t   = threadIdx.x;
    int sub = t >> 4;          // row slot 0..15
    int l   = t & 15;          // 8 channels per lane
    int row = blockIdx.x * 16 + sub;
    const int* rp; const int* pm; const int* col; const float* val;
    const u32* fin; u32* fout;
    if (blockIdx.y == 0){ rp=rpA; pm=pmA; col=colA; val=valA; fin=finA; fout=foutA; }
    else                { rp=rpB; pm=pmB; col=colB; val=valB; fin=finB; fout=foutB; }
    if (row >= M_SIMP) return;
    int s = rp[row], e = rp[row + 1];
    float a0=0,a1=0,a2=0,a3=0,a4=0,a5=0,a6=0,a7=0;
    int j = s;
    for (; j + 4 <= e; j += 4){
        int e0 = pm[j], e1 = pm[j+1], e2 = pm[j+2], e3 = pm[j+3];
        int c0 = col[e0], c1 = col[e1], c2 = col[e2], c3 = col[e3];
        uint4 g0 = *(const uint4*)(fin + (size_t)c0 * 64 + l * 4);
        uint4 g1 = *(const uint4*)(fin + (size_t)c1 * 64 + l * 4);
        uint4 g2 = *(const uint4*)(fin + (size_t)c2 * 64 + l * 4);
        uint4 g3 = *(const uint4*)(fin + (size_t)c3 * 64 + l * 4);
        float v0 = val[e0], v1 = val[e1], v2 = val[e2], v3 = val[e3];
        a0 += v0*bf2f(g0.x&0xffffu) + v1*bf2f(g1.x&0xffffu) + v2*bf2f(g2.x&0xffffu) + v3*bf2f(g3.x&0xffffu);
        a1 += v0*bf2f(g0.x>>16)     + v1*bf2f(g1.x>>16)     + v2*bf2f(g2.x>>16)     + v3*bf2f(g3.x>>16);
        a2 += v0*bf2f(g0.y&0xffffu) + v1*bf2f(g1.y&0xffffu) + v2*bf2f(g2.y&0xffffu) + v3*bf2f(g3.y&0xffffu);
        a3 += v0*bf2f(g0.y>>16)     + v1*bf2f(g1.y>>16)     + v2*bf2f(g2.y>>16)     + v3*bf2f(g3.y>>16);
        a4 += v0*bf2f(g0.z&0xffffu) + v1*bf2f(g1.z&0xffffu) + v2*bf2f(g2.z&0xffffu) + v3*bf2f(g3.z&0xffffu);
        a5 += v0*bf2f(g0.z>>16)     + v1*bf2f(g1.z>>16)     + v2*bf2f(g2.z>>16)     + v3*bf2f(g3.z>>16);
        a6 += v0*bf2f(g0.w&0xffffu) + v1*bf2f(g1.w&0xffffu) + v2*bf2f(g2.w&0xffffu) + v3*bf2f(g3.w&0xffffu);
        a7 += v0*bf2f(g0.w>>16)     + v1*bf2f(g1.w>>16)     + v2*bf2f(g2.w>>16)     + v3*bf2f(g3.w>>16);
    }
    for (; j < e; j++){
        int ee = pm[j];
        int c  = col[ee];
        float v = val[ee];
        uint4 g = *(const uint4*)(fin + (size_t)c * 64 + l * 4);
        a0 += v*bf2f(g.x&0xffffu); a1 += v*bf2f(g.x>>16);
        a2 += v*bf2f(g.y&0xffffu); a3 += v*bf2f(g.y>>16);
        a4 += v*bf2f(g.z&0xffffu); a5 += v*bf2f(g.z>>16);
        a6 += v*bf2f(g.w&0xffffu); a7 += v*bf2f(g.w>>16);
    }
    uint4 o;
    o.x = f2bf(a0) | (f2bf(a1) << 16);
    o.y = f2bf(a2) | (f2bf(a3) << 16);
    o.z = f2bf(a4) | (f2bf(a5) << 16);
    o.w = f2bf(a6) | (f2bf(a7) << 16);
    *(uint4*)(fout + (size_t)row * 64 + l * 4) = o;
}

// ---------------- theta (o,i,k) fp32 -> Wb bf16 [k][o][i] packed u32 ----------------
__global__ void k_wb(const float* __restrict__ theta, u32* __restrict__ Wb){
    int idx = blockIdx.x * 256 + threadIdx.x;
    if (idx < KTOT * 64 * 32){
        int km = idx >> 11;
        int r  = idx & 2047;
        int o  = r >> 5;
        int i2 = (r & 31) * 2;
        u32 lo = f2bf(theta[o * 384 + i2 * 6 + km]);
        u32 hi = f2bf(theta[o * 384 + (i2 + 1) * 6 + km]);
        Wb[idx] = lo | (hi << 16);
    }
}

// ---------------- MFMA GEMM ----------------
__global__ __launch_bounds__(256) void k_gemm(
    const u32* __restrict__ F0, const u32* __restrict__ F1, const u32* __restrict__ F2,
    const u32* __restrict__ F4, const u32* __restrict__ F5,
    const u32* __restrict__ Wb, const float* __restrict__ bias, float* __restrict__ out)
{
    int t    = threadIdx.x;
    int wave = t >> 6;
    int lane = t & 63;
    int q    = lane >> 4;
    int l16  = lane & 15;
    int bm   = blockIdx.x * 64;
    int b    = blockIdx.y;
    const u32* __restrict__ Fs[6] = {F0, F1, F2, F0, F4, F5};

    f32x4 acc0 = {0.f,0.f,0.f,0.f}, acc1 = {0.f,0.f,0.f,0.f};
    f32x4 acc2 = {0.f,0.f,0.f,0.f}, acc3 = {0.f,0.f,0.f,0.f};

    int o_a = wave * 16 + l16;
    size_t mr0 = (size_t)(bm +  0 + l16) * 64 + b * 32;
    size_t mr1 = (size_t)(bm + 16 + l16) * 64 + b * 32;
    size_t mr2 = (size_t)(bm + 32 + l16) * 64 + b * 32;
    size_t mr3 = (size_t)(bm + 48 + l16) * 64 + b * 32;

    #pragma unroll
    for (int km = 0; km < KTOT; km++){
        const u32* __restrict__ F = Fs[km];
        const u32* __restrict__ W = Wb + (km * 64 + o_a) * 32;
        #pragma unroll
        for (int h = 0; h < 2; h++){
            int koff = h * 16 + q * 4;
            short8 a   = *(const short8*)(W + koff);
            short8 bb0 = *(const short8*)(F + mr0 + koff);
            short8 bb1 = *(const short8*)(F + mr1 + koff);
            short8 bb2 = *(const short8*)(F + mr2 + koff);
            short8 bb3 = *(const short8*)(F + mr3 + koff);
            acc0 = __builtin_amdgcn_mfma_f32_16x16x32_bf16(a, bb0, acc0, 0, 0, 0);
            acc1 = __builtin_amdgcn_mfma_f32_16x16x32_bf16(a, bb1, acc1, 0, 0, 0);
            acc2 = __builtin_amdgcn_mfma_f32_16x16x32_bf16(a, bb2, acc2, 0, 0, 0);
            acc3 = __builtin_amdgcn_mfma_f32_16x16x32_bf16(a, bb3, acc3, 0, 0, 0);
        }
    }

    int ob = wave * 16 + q * 4;
    float bv0 = bias[ob], bv1 = bias[ob+1], bv2 = bias[ob+2], bv3 = bias[ob+3];
    f32x4 accs[4] = {acc0, acc1, acc2, acc3};
    #pragma unroll
    for (int ms = 0; ms < 4; ms++){
        int gm = bm + ms * 16 + l16;
        if (gm < M_SIMP){
            size_t base = (size_t)(b * 64 + ob) * M_SIMP + gm;
            out[base             ] = accs[ms][0] + bv0;
            out[base + 1ul*M_SIMP] = accs[ms][1] + bv1;
            out[base + 2ul*M_SIMP] = accs[ms][2] + bv2;
            out[base + 3ul*M_SIMP] = accs[ms][3] + bv3;
        }
    }
}

extern "C" void kernel_launch(void* const* d_in, const int* in_sizes, int n_in,
                              void* d_out, int out_size, void* d_ws, size_t ws_size,
                              hipStream_t stream)
{
    const int*   Ll_idx = (const int*)d_in[0];
    const float* Ll_val = (const float*)d_in[1];
    const int*   Lu_idx = (const int*)d_in[2];
    const float* Lu_val = (const float*)d_in[3];
    const float* x      = (const float*)d_in[4];
    const float* theta  = (const float*)d_in[5];
    const float* bias   = (const float*)d_in[6];
    float* out = (float*)d_out;

    char* ws = (char*)d_ws;
    size_t off = 0;
    auto take = [&](size_t bytes) -> char* {
        char* p = ws + off;
        off = (off + bytes + 255) & ~(size_t)255;
        return p;
    };
    const size_t FB = (size_t)MPAD * 64 * 4;
    u32* F0 = (u32*)take(FB);
    u32* F1 = (u32*)take(FB);
    u32* F2 = (u32*)take(FB);
    u32* F4 = (u32*)take(FB);
    u32* F5 = (u32*)take(FB);
    u32* Wb = (u32*)take((size_t)KTOT * 64 * 32 * 4);
    int* cnt_l = (int*)take((size_t)M_SIMP * 4);
    int* cnt_u = (int*)take((size_t)M_SIMP * 4);
    int* rp_l  = (int*)take((size_t)(M_SIMP + 1) * 4);
    int* rp_u  = (int*)take((size_t)(M_SIMP + 1) * 4);
    int* pe_l  = (int*)take((size_t)NNZV * 4);
    int* pe_u  = (int*)take((size_t)NNZV * 4);
    int* pm_l  = (int*)take((size_t)NNZV * 4);
    int* pm_u  = (int*)take((size_t)NNZV * 4);
    int* bs_l = (int*)take(512);
    int* bs_u = (int*)take(512);

    hipMemsetAsync(cnt_l, 0, (size_t)M_SIMP * 4, stream);
    hipMemsetAsync(cnt_u, 0, (size_t)M_SIMP * 4, stream);

    const int NBH = (NNZV + 255) / 256;       // 3125
    dim3 gh(NBH, 2);
    k_histpe<<<gh, 256, 0, stream>>>(Ll_idx, cnt_l, pe_l, Lu_idx, cnt_u, pe_u);

    const int NBS = (M_SIMP + 1023) / 1024;   // 98
    dim3 gs(NBS, 2);
    k_scan1<<<gs, 256, 0, stream>>>(cnt_l, rp_l, bs_l, cnt_u, rp_u, bs_u, M_SIMP);
    k_scan2<<<1, 64, 0, stream>>>(bs_l, bs_u, rp_l, rp_u, NBS);
    k_scan3<<<gs, 256, 0, stream>>>(rp_l, bs_l, rp_u, bs_u, M_SIMP);

    k_perm<<<gh, 256, 0, stream>>>(Ll_idx, pe_l, rp_l, pm_l,
                                   Lu_idx, pe_u, rp_u, pm_u);

    const int NBT = (M_SIMP + 63) / 64;       // 1563
    k_transpose<<<NBT, 256, 0, stream>>>(x, F0);
    k_wb<<<(KTOT * 64 * 32 + 255) / 256, 256, 0, stream>>>(theta, Wb);

    const int NBM = (M_SIMP + 15) / 16;       // 6250
    dim3 gm(NBM, 2);
    k_spmm<<<gm, 256, 0, stream>>>(rp_l, pm_l, Ll_idx + NNZV, Ll_val, F0, F1,
                                   rp_u, pm_u, Lu_idx + NNZV, Lu_val, F0, F4);
    k_spmm<<<gm, 256, 0, stream>>>(rp_l, pm_l, Ll_idx + NNZV, Ll_val, F1, F2,
                                   rp_u, pm_u, Lu_idx + NNZV, Lu_val, F4, F5);

    dim3 gg(NBT, 2);
    k_gemm<<<gg, 256, 0, stream>>>(F0, F1, F2, F4, F5, Wb, bias, out);
}